// Round 2
// baseline (801.114 us; speedup 1.0000x reference)
//
#include <hip/hip_runtime.h>
#include <hip/hip_bf16.h>

using bf16 = __hip_bfloat16;

__device__ __forceinline__ float b2f(bf16 v){ return __bfloat162float(v); }
__device__ __forceinline__ float sigf(float v){ return 1.f/(1.f + __expf(-v)); }
__device__ __forceinline__ float ldv(const float* p, int i){ return p[i]; }
__device__ __forceinline__ float ldv(const bf16* p, int i){ return b2f(p[i]); }
__device__ __forceinline__ void stv(float* p, int i, float v){ p[i] = v; }
__device__ __forceinline__ void stv(bf16* p, int i, float v){ p[i] = __float2bfloat16(v); }

// ---------------------------------------------------------------------------
// K0: dtype detect. Scan first 16384 halfwords of x for bf16 NaN/Inf bit
// patterns (exp field == 0xFF). Genuine bf16 N(0,1) data: none. f32 data
// read as halfwords: ~1/256 of low halves -> ~32 hits. flag=1 => f32.
// ---------------------------------------------------------------------------
__global__ __launch_bounds__(256) void k_detect(const unsigned short* xs, int* flag){
  __shared__ int cnt;
  if (threadIdx.x == 0) cnt = 0;
  __syncthreads();
  int local = 0;
  for (int i = threadIdx.x; i < 16384; i += 256){
    if (((xs[i] >> 7) & 0xFF) == 0xFF) local++;
  }
  if (local) atomicAdd(&cnt, local);
  __syncthreads();
  if (threadIdx.x == 0) *flag = (cnt > 0) ? 1 : 0;
}

// ---------------------------------------------------------------------------
// K0b: canonicalize all 18 param tensors to fp32 in ws (dual-mode load).
// grid (96, 18): blockIdx.y = tensor id, grid-stride within.
// ---------------------------------------------------------------------------
struct ParamSrc { const void* p[18]; };

__global__ __launch_bounds__(256) void k_convert(ParamSrc ps, const int* flagp,
                                                 float* cpar){
  static constexpr int n[18]   = {41472,18,147456,131072,147456,64,64,64,64,64,
                                  16384,256,65536,256,256,256,256,256};
  static constexpr int off[18] = {0,41472,41504,188960,320032,467488,467552,467616,
                                  467680,467744,467808,484192,484448,549984,550240,
                                  550496,550752,551008};
  const int s = blockIdx.y;
  const bool f32 = (*flagp != 0);
  float* dst = cpar + off[s];
  if (f32){
    const float* src = (const float*)ps.p[s];
    for (int i = blockIdx.x * 256 + threadIdx.x; i < n[s]; i += gridDim.x * 256)
      dst[i] = src[i];
  } else {
    const bf16* src = (const bf16*)ps.p[s];
    for (int i = blockIdx.x * 256 + threadIdx.x; i < n[s]; i += gridDim.x * 256)
      dst[i] = b2f(src[i]);
  }
}

// ---------------------------------------------------------------------------
// K1: offset conv: 3x3, Cin=256, Cout=18, pad=1, bias. 2 co per block.
// grid (16 ptiles, 9 cogroups, 4 b), 256 thr. Weights staged in LDS.
// ---------------------------------------------------------------------------
template<typename T>
__device__ __forceinline__ void conv_off_body(const T* __restrict__ x,
    const float* __restrict__ cw, const float* __restrict__ cb,
    float* __restrict__ offc){
  const int b = blockIdx.z, cog = blockIdx.y, pt = blockIdx.x;
  const int co0 = cog * 2;
  __shared__ __align__(16) float wsh[2304 * 2];
  for (int i = threadIdx.x; i < 4608; i += 256){
    int ct = i >> 1, j = i & 1;
    wsh[i] = cw[(co0 + j) * 2304 + ct];
  }
  __syncthreads();
  const int p = pt * 256 + threadIdx.x;
  const int y = p >> 6, xx = p & 63;
  float a0 = cb[co0], a1 = cb[co0 + 1];
  const T* xb = x + b * 256 * 4096;
  for (int ci = 0; ci < 256; ci++){
    const T* xc = xb + ci * 4096;
    #pragma unroll
    for (int t = 0; t < 9; t++){
      int yy = y + t / 3 - 1, xp = xx + t % 3 - 1;
      float xv = ((unsigned)yy < 64u && (unsigned)xp < 64u) ? ldv(xc, yy * 64 + xp) : 0.f;
      float2 wv = *(const float2*)(wsh + (ci * 9 + t) * 2);
      a0 += xv * wv.x; a1 += xv * wv.y;
    }
  }
  offc[(b * 18 + co0) * 4096 + p] = a0;
  offc[(b * 18 + co0 + 1) * 4096 + p] = a1;
}

__global__ __launch_bounds__(256) void k_conv_off(const void* x, const int* flagp,
    const float* cw, const float* cb, float* offc){
  if (*flagp) conv_off_body((const float*)x, cw, cb, offc);
  else        conv_off_body((const bf16*)x, cw, cb, offc);
}

// ---------------------------------------------------------------------------
// K2: deformable conv, groups=4, K=9, Cg=64. Block = 8 consecutive pixels.
// Phase1: bilinear params. Phase2: gather cols -> LDS (bf16, 37KB).
// Phase3: thread t = output channel co, 8 accumulators (one per pixel).
// grid 2048 blocks (B*HW/8), 256 thr.
// ---------------------------------------------------------------------------
template<typename T>
__device__ __forceinline__ void deform_body(const T* __restrict__ x,
    const float* __restrict__ offc, const float* __restrict__ cw,
    float* __restrict__ xdir){
  __shared__ int   s_y0[9][8], s_x0[9][8];
  __shared__ float s_wy[9][8], s_wx[9][8];
  __shared__ __align__(16) unsigned short cols[2304 * 8];
  const int q0 = blockIdx.x * 8;
  const int b = q0 >> 12, p0 = q0 & 4095;
  const int t = threadIdx.x;
  if (t < 72){
    int k = t >> 3, pos = t & 7;
    int p = p0 + pos;
    int y = p >> 6, xx = p & 63;
    const float* ob = offc + b * 18 * 4096;
    float dy = ob[(2 * k) * 4096 + p];
    float dx = ob[(2 * k + 1) * 4096 + p];
    float py = (float)(y + k / 3 - 1) + dy;
    float px = (float)(xx + k % 3 - 1) + dx;
    float y0f = floorf(py), x0f = floorf(px);
    s_y0[k][pos] = (int)y0f; s_x0[k][pos] = (int)x0f;
    s_wy[k][pos] = py - y0f; s_wx[k][pos] = px - x0f;
  }
  __syncthreads();
  {
    const int pos = t & 7, cb = t >> 3;
    #pragma unroll
    for (int u = 0; u < 8; u++){
      int c = cb + u * 32;
      const T* xc = x + (b * 256 + c) * 4096;
      #pragma unroll
      for (int k = 0; k < 9; k++){
        int y0 = s_y0[k][pos], x0 = s_x0[k][pos];
        float wy = s_wy[k][pos], wx = s_wx[k][pos];
        float v00 = ((unsigned)y0 < 64u && (unsigned)x0 < 64u) ? ldv(xc, y0*64 + x0) : 0.f;
        float v01 = ((unsigned)y0 < 64u && (unsigned)(x0+1) < 64u) ? ldv(xc, y0*64 + x0 + 1) : 0.f;
        float v10 = ((unsigned)(y0+1) < 64u && (unsigned)x0 < 64u) ? ldv(xc, (y0+1)*64 + x0) : 0.f;
        float v11 = ((unsigned)(y0+1) < 64u && (unsigned)(x0+1) < 64u) ? ldv(xc, (y0+1)*64 + x0 + 1) : 0.f;
        float val = v00*(1.f-wy)*(1.f-wx) + v01*(1.f-wy)*wx
                  + v10*wy*(1.f-wx)       + v11*wy*wx;
        bf16 hv = __float2bfloat16(val);
        cols[(c * 9 + k) * 8 + pos] = *(unsigned short*)&hv;
      }
    }
  }
  __syncthreads();
  {
    const int co = t, g = t >> 6;
    const float* wrow = cw + co * 576;
    const unsigned short* cgp = cols + g * 576 * 8;
    float acc[8] = {0,0,0,0,0,0,0,0};
    for (int ck = 0; ck < 576; ck += 4){
      float4 wq = *(const float4*)(wrow + ck);
      float wv[4] = {wq.x, wq.y, wq.z, wq.w};
      #pragma unroll
      for (int u = 0; u < 4; u++){
        uint4 cp = *(const uint4*)(cgp + (ck + u) * 8);
        float w8 = wv[u];
        acc[0] += w8 * __uint_as_float(cp.x << 16);
        acc[1] += w8 * __uint_as_float(cp.x & 0xffff0000u);
        acc[2] += w8 * __uint_as_float(cp.y << 16);
        acc[3] += w8 * __uint_as_float(cp.y & 0xffff0000u);
        acc[4] += w8 * __uint_as_float(cp.z << 16);
        acc[5] += w8 * __uint_as_float(cp.z & 0xffff0000u);
        acc[6] += w8 * __uint_as_float(cp.w << 16);
        acc[7] += w8 * __uint_as_float(cp.w & 0xffff0000u);
      }
    }
    float* xo = xdir + (b * 256 + co) * 4096 + p0;
    #pragma unroll
    for (int pos = 0; pos < 8; pos++) xo[pos] = acc[pos];
  }
}

__global__ __launch_bounds__(256) void k_deform(const void* x, const int* flagp,
    const float* offc, const float* cw, float* xdir){
  if (*flagp) deform_body((const float*)x, offc, cw, xdir);
  else        deform_body((const bf16*)x, offc, cw, xdir);
}

// ---------------------------------------------------------------------------
// K3: 1x1 conv over concat([x_dir, x_prev]) with w_cross (256x512), no bias.
// Block: 64 pixels x 64 co; thread: 4x4 microtile. grid (256, 4), 256 thr.
// ---------------------------------------------------------------------------
template<typename T>
__device__ __forceinline__ void cross_body(const float* __restrict__ xdir,
    const T* __restrict__ xprev, const float* __restrict__ wc,
    float* __restrict__ xdense){
  const int q0 = blockIdx.x * 64;
  const int b = q0 >> 12, p0 = q0 & 4095;
  const int cg = blockIdx.y;
  const int t = threadIdx.x;
  const int pg = t & 15, cog = t >> 4;
  const int co_b = cg * 64 + cog * 4;
  __shared__ __align__(16) float xs[32 * 64];
  float acc[16];
  #pragma unroll
  for (int i = 0; i < 16; i++) acc[i] = 0.f;
  for (int cc = 0; cc < 512; cc += 32){
    __syncthreads();
    for (int i = t; i < 2048; i += 256){
      int cl = i >> 6, pp = i & 63;
      int ci = cc + cl;
      xs[i] = (ci < 256) ? xdir[(b * 256 + ci) * 4096 + p0 + pp]
                         : ldv(xprev, (b * 256 + ci - 256) * 4096 + p0 + pp);
    }
    __syncthreads();
    for (int cl = 0; cl < 32; cl++){
      float4 xv = *(const float4*)(xs + cl * 64 + pg * 4);
      int ci = cc + cl;
      float w0 = wc[(co_b + 0) * 512 + ci];
      float w1 = wc[(co_b + 1) * 512 + ci];
      float w2 = wc[(co_b + 2) * 512 + ci];
      float w3 = wc[(co_b + 3) * 512 + ci];
      acc[ 0] += w0*xv.x; acc[ 1] += w0*xv.y; acc[ 2] += w0*xv.z; acc[ 3] += w0*xv.w;
      acc[ 4] += w1*xv.x; acc[ 5] += w1*xv.y; acc[ 6] += w1*xv.z; acc[ 7] += w1*xv.w;
      acc[ 8] += w2*xv.x; acc[ 9] += w2*xv.y; acc[10] += w2*xv.z; acc[11] += w2*xv.w;
      acc[12] += w3*xv.x; acc[13] += w3*xv.y; acc[14] += w3*xv.z; acc[15] += w3*xv.w;
    }
  }
  #pragma unroll
  for (int j = 0; j < 4; j++){
    float4 v; v.x = acc[j*4+0]; v.y = acc[j*4+1]; v.z = acc[j*4+2]; v.w = acc[j*4+3];
    *(float4*)(xdense + (b * 256 + co_b + j) * 4096 + p0 + pg * 4) = v;
  }
}

__global__ __launch_bounds__(256) void k_cross(const float* xdir, const void* xprev,
    const int* flagp, const float* wc, float* xdense){
  if (*flagp) cross_body(xdir, (const float*)xprev, wc, xdense);
  else        cross_body(xdir, (const bf16*)xprev, wc, xdense);
}

// ---------------------------------------------------------------------------
// K4: 3x3 conv 256->64 + bias + BN + SiLU. 4 co per block, weights in LDS.
// grid (16 ptiles, 16 cogroups, 4 b), 256 thr.
// ---------------------------------------------------------------------------
__global__ __launch_bounds__(256) void k_g1(
    const float* __restrict__ xdense, const float* __restrict__ cw,
    const float* __restrict__ cb,
    const float* __restrict__ gam, const float* __restrict__ bet,
    const float* __restrict__ mea, const float* __restrict__ var,
    float* __restrict__ abuf){
  const int b = blockIdx.z, cog = blockIdx.y, pt = blockIdx.x;
  const int co0 = cog * 4;
  __shared__ __align__(16) float wsh[2304 * 4];
  for (int i = threadIdx.x; i < 9216; i += 256){
    int ct = i >> 2, j = i & 3;
    wsh[i] = cw[(co0 + j) * 2304 + ct];
  }
  __syncthreads();
  const int p = pt * 256 + threadIdx.x;
  const int y = p >> 6, xx = p & 63;
  float acc[4] = {0,0,0,0};
  const float* xb = xdense + b * 256 * 4096;
  for (int ci = 0; ci < 256; ci++){
    const float* xc = xb + ci * 4096;
    #pragma unroll
    for (int t = 0; t < 9; t++){
      int yy = y + t / 3 - 1, xp = xx + t % 3 - 1;
      float xv = ((unsigned)yy < 64u && (unsigned)xp < 64u) ? xc[yy * 64 + xp] : 0.f;
      float4 wv = *(const float4*)(wsh + (ci * 9 + t) * 4);
      acc[0] += xv * wv.x; acc[1] += xv * wv.y; acc[2] += xv * wv.z; acc[3] += xv * wv.w;
    }
  }
  #pragma unroll
  for (int j = 0; j < 4; j++){
    int co = co0 + j;
    float v = acc[j] + cb[co];
    float inv = gam[co] * rsqrtf(var[co] + 1e-5f);
    v = v * inv + (bet[co] - mea[co] * inv);
    abuf[(b * 64 + co) * 4096 + p] = v * sigf(v);
  }
}

// ---------------------------------------------------------------------------
// K5: 1x1 conv 64->256 + bias + sigmoid, then xa = xdense * attn (fused).
// grid (64 ptiles, 64 cogroups of 4), 256 thr.
// ---------------------------------------------------------------------------
__global__ __launch_bounds__(256) void k_attn(
    const float* __restrict__ abuf, const float* __restrict__ cw,
    const float* __restrict__ cb, const float* __restrict__ xdense,
    float* __restrict__ xa){
  const int q0 = blockIdx.x * 256;
  const int b = q0 >> 12, p0 = q0 & 4095;
  const int co0 = blockIdx.y * 4;
  const int p = p0 + threadIdx.x;
  float acc[4] = {0,0,0,0};
  const float* ab = abuf + b * 64 * 4096;
  for (int c = 0; c < 64; c++){
    float av = ab[c * 4096 + p];
    acc[0] += cw[(co0 + 0) * 64 + c] * av;
    acc[1] += cw[(co0 + 1) * 64 + c] * av;
    acc[2] += cw[(co0 + 2) * 64 + c] * av;
    acc[3] += cw[(co0 + 3) * 64 + c] * av;
  }
  #pragma unroll
  for (int j = 0; j < 4; j++){
    int co = co0 + j;
    float attn = sigf(acc[j] + cb[co]);
    int idx = (b * 256 + co) * 4096 + p;
    xa[idx] = xdense[idx] * attn;
  }
}

// ---------------------------------------------------------------------------
// K6: 1x1 conv 256->256 + bias + BN + SiLU + residual, dual-mode store.
// Same GEMM structure as K3. grid (256, 4), 256 thr.
// ---------------------------------------------------------------------------
template<typename T>
__device__ __forceinline__ void out_body(const float* __restrict__ xa,
    const float* __restrict__ wo, const float* __restrict__ cb,
    const float* __restrict__ gam, const float* __restrict__ bet,
    const float* __restrict__ mea, const float* __restrict__ var,
    const T* __restrict__ xres, T* __restrict__ out){
  const int q0 = blockIdx.x * 64;
  const int b = q0 >> 12, p0 = q0 & 4095;
  const int cg = blockIdx.y;
  const int t = threadIdx.x;
  const int pg = t & 15, cog = t >> 4;
  const int co_b = cg * 64 + cog * 4;
  __shared__ __align__(16) float xs[32 * 64];
  float acc[16];
  #pragma unroll
  for (int i = 0; i < 16; i++) acc[i] = 0.f;
  for (int cc = 0; cc < 256; cc += 32){
    __syncthreads();
    for (int i = t; i < 2048; i += 256){
      int cl = i >> 6, pp = i & 63;
      xs[i] = xa[(b * 256 + cc + cl) * 4096 + p0 + pp];
    }
    __syncthreads();
    for (int cl = 0; cl < 32; cl++){
      float4 xv = *(const float4*)(xs + cl * 64 + pg * 4);
      int ci = cc + cl;
      float w0 = wo[(co_b + 0) * 256 + ci];
      float w1 = wo[(co_b + 1) * 256 + ci];
      float w2 = wo[(co_b + 2) * 256 + ci];
      float w3 = wo[(co_b + 3) * 256 + ci];
      acc[ 0] += w0*xv.x; acc[ 1] += w0*xv.y; acc[ 2] += w0*xv.z; acc[ 3] += w0*xv.w;
      acc[ 4] += w1*xv.x; acc[ 5] += w1*xv.y; acc[ 6] += w1*xv.z; acc[ 7] += w1*xv.w;
      acc[ 8] += w2*xv.x; acc[ 9] += w2*xv.y; acc[10] += w2*xv.z; acc[11] += w2*xv.w;
      acc[12] += w3*xv.x; acc[13] += w3*xv.y; acc[14] += w3*xv.z; acc[15] += w3*xv.w;
    }
  }
  #pragma unroll
  for (int j = 0; j < 4; j++){
    int co = co_b + j;
    float inv = gam[co] * rsqrtf(var[co] + 1e-5f);
    float sh  = bet[co] - mea[co] * inv;
    float bs  = cb[co];
    #pragma unroll
    for (int i = 0; i < 4; i++){
      float v = acc[j * 4 + i] + bs;
      v = v * inv + sh;
      v = v * sigf(v);
      int p = p0 + pg * 4 + i;
      int idx = (b * 256 + co) * 4096 + p;
      stv(out, idx, v + ldv(xres, idx));
    }
  }
}

__global__ __launch_bounds__(256) void k_out(const float* xa, const float* wo,
    const float* cb, const float* gam, const float* bet, const float* mea,
    const float* var, const void* xres, void* out, const int* flagp){
  if (*flagp) out_body(xa, wo, cb, gam, bet, mea, var, (const float*)xres, (float*)out);
  else        out_body(xa, wo, cb, gam, bet, mea, var, (const bf16*)xres, (bf16*)out);
}

// ---------------------------------------------------------------------------
extern "C" void kernel_launch(void* const* d_in, const int* in_sizes, int n_in,
                              void* d_out, int out_size, void* d_ws, size_t ws_size,
                              hipStream_t stream) {
  const void* x      = d_in[0];
  const void* x_prev = d_in[1];

  float* ws   = (float*)d_ws;
  int*   flag = (int*)ws;                 // ws[0..15] reserved
  float* cpar = ws + 16;                  // canonical fp32 params (551264 f)
  // canonical param offsets (padded to 16)
  float* cw_off   = cpar + 0;
  float* cb_off   = cpar + 41472;
  float* cw_def   = cpar + 41504;
  float* cw_cross = cpar + 188960;
  float* cw_g1    = cpar + 320032;
  float* cb_g1    = cpar + 467488;
  float* cg1_gam  = cpar + 467552;
  float* cg1_bet  = cpar + 467616;
  float* cg1_mea  = cpar + 467680;
  float* cg1_var  = cpar + 467744;
  float* cw_g2    = cpar + 467808;
  float* cb_g2    = cpar + 484192;
  float* cw_out   = cpar + 484448;
  float* cb_out   = cpar + 549984;
  float* co_gam   = cpar + 550240;
  float* co_bet   = cpar + 550496;
  float* co_mea   = cpar + 550752;
  float* co_var   = cpar + 551008;

  float* base   = ws + 16 + 551264;
  float* offc   = base;                   // 4*18*4096  = 294912 f
  float* xdir   = offc + 294912;          // 4*256*4096 = 4194304 f
  float* xdense = xdir + 4194304;         // 4194304 f
  float* abuf   = xdense + 4194304;       // 1048576 f
  float* xa     = xdir;                   // reuse (xdir dead after K3)

  ParamSrc ps;
  for (int i = 0; i < 18; i++) ps.p[i] = d_in[2 + i];

  k_detect<<<dim3(1), 256, 0, stream>>>((const unsigned short*)x, flag);
  k_convert<<<dim3(96, 18), 256, 0, stream>>>(ps, flag, cpar);
  k_conv_off<<<dim3(16, 9, 4), 256, 0, stream>>>(x, flag, cw_off, cb_off, offc);
  k_deform<<<dim3(2048), 256, 0, stream>>>(x, flag, offc, cw_def, xdir);
  k_cross<<<dim3(256, 4), 256, 0, stream>>>(xdir, x_prev, flag, cw_cross, xdense);
  k_g1<<<dim3(16, 16, 4), 256, 0, stream>>>(xdense, cw_g1, cb_g1, cg1_gam, cg1_bet,
                                            cg1_mea, cg1_var, abuf);
  k_attn<<<dim3(64, 64), 256, 0, stream>>>(abuf, cw_g2, cb_g2, xdense, xa);
  k_out<<<dim3(256, 4), 256, 0, stream>>>(xa, cw_out, cb_out, co_gam, co_bet,
                                          co_mea, co_var, x, d_out, flag);
}

// Round 3
// 662.698 us; speedup vs baseline: 1.2089x; 1.2089x over previous
//
#include <hip/hip_runtime.h>
#include <hip/hip_bf16.h>

using bf16 = __hip_bfloat16;
typedef __attribute__((ext_vector_type(8))) short short8;
typedef __attribute__((ext_vector_type(4))) float f32x4;

__device__ __forceinline__ float b2f(bf16 v){ return __bfloat162float(v); }
__device__ __forceinline__ float sigf(float v){ return 1.f/(1.f + __expf(-v)); }
__device__ __forceinline__ float ldv(const float* p, int i){ return p[i]; }
__device__ __forceinline__ float ldv(const bf16* p, int i){ return b2f(p[i]); }
__device__ __forceinline__ void stv(float* p, int i, float v){ p[i] = v; }
__device__ __forceinline__ void stv(bf16* p, int i, float v){ p[i] = __float2bfloat16(v); }

// ---------------------------------------------------------------------------
// K0: dtype detect. Scan first 16384 halfwords of x for bf16 NaN/Inf bit
// patterns (exp field == 0xFF). flag=1 => inputs are f32.
// ---------------------------------------------------------------------------
__global__ __launch_bounds__(256) void k_detect(const unsigned short* xs, int* flag){
  __shared__ int cnt;
  if (threadIdx.x == 0) cnt = 0;
  __syncthreads();
  int local = 0;
  for (int i = threadIdx.x; i < 16384; i += 256){
    if (((xs[i] >> 7) & 0xFF) == 0xFF) local++;
  }
  if (local) atomicAdd(&cnt, local);
  __syncthreads();
  if (threadIdx.x == 0) *flag = (cnt > 0) ? 1 : 0;
}

// ---------------------------------------------------------------------------
// K0b: canonicalize 18 param tensors to fp32 in ws; slot 18 = w_def -> bf16.
// grid (96, 19).
// ---------------------------------------------------------------------------
struct ParamSrc { const void* p[18]; };

__global__ __launch_bounds__(256) void k_convert(ParamSrc ps, const int* flagp,
                                                 float* cpar, bf16* wdefb){
  static constexpr int n[19]   = {41472,18,147456,131072,147456,64,64,64,64,64,
                                  16384,256,65536,256,256,256,256,256,147456};
  static constexpr int off[19] = {0,41472,41504,188960,320032,467488,467552,467616,
                                  467680,467744,467808,484192,484448,549984,550240,
                                  550496,550752,551008,0};
  const int s = blockIdx.y;
  const bool f32 = (*flagp != 0);
  const int src_slot = (s == 18) ? 2 : s;   // slot 18 re-reads w_def
  if (s == 18){
    if (f32){
      const float* src = (const float*)ps.p[src_slot];
      for (int i = blockIdx.x * 256 + threadIdx.x; i < n[s]; i += gridDim.x * 256)
        wdefb[i] = __float2bfloat16(src[i]);
    } else {
      const bf16* src = (const bf16*)ps.p[src_slot];
      for (int i = blockIdx.x * 256 + threadIdx.x; i < n[s]; i += gridDim.x * 256)
        wdefb[i] = src[i];
    }
    return;
  }
  float* dst = cpar + off[s];
  if (f32){
    const float* src = (const float*)ps.p[s];
    for (int i = blockIdx.x * 256 + threadIdx.x; i < n[s]; i += gridDim.x * 256)
      dst[i] = src[i];
  } else {
    const bf16* src = (const bf16*)ps.p[s];
    for (int i = blockIdx.x * 256 + threadIdx.x; i < n[s]; i += gridDim.x * 256)
      dst[i] = b2f(src[i]);
  }
}

// ---------------------------------------------------------------------------
// K1: offset conv: 3x3, Cin=256, Cout=18, pad=1, bias. 2 co per block.
// grid (16 ptiles, 9 cogroups, 4 b), 256 thr. Shared decl in wrapper (no dup).
// ---------------------------------------------------------------------------
template<typename T>
__device__ __forceinline__ void conv_off_body(const T* __restrict__ x,
    const float* __restrict__ cw, const float* __restrict__ cb,
    float* __restrict__ offc, float* wsh){
  const int b = blockIdx.z, cog = blockIdx.y, pt = blockIdx.x;
  const int co0 = cog * 2;
  for (int i = threadIdx.x; i < 4608; i += 256){
    int ct = i >> 1, j = i & 1;
    wsh[i] = cw[(co0 + j) * 2304 + ct];
  }
  __syncthreads();
  const int p = pt * 256 + threadIdx.x;
  const int y = p >> 6, xx = p & 63;
  float a0 = cb[co0], a1 = cb[co0 + 1];
  const T* xb = x + b * 256 * 4096;
  for (int ci = 0; ci < 256; ci++){
    const T* xc = xb + ci * 4096;
    #pragma unroll
    for (int t = 0; t < 9; t++){
      int yy = y + t / 3 - 1, xp = xx + t % 3 - 1;
      float xv = ((unsigned)yy < 64u && (unsigned)xp < 64u) ? ldv(xc, yy * 64 + xp) : 0.f;
      float2 wv = *(const float2*)(wsh + (ci * 9 + t) * 2);
      a0 += xv * wv.x; a1 += xv * wv.y;
    }
  }
  offc[(b * 18 + co0) * 4096 + p] = a0;
  offc[(b * 18 + co0 + 1) * 4096 + p] = a1;
}

__global__ __launch_bounds__(256) void k_conv_off(const void* x, const int* flagp,
    const float* cw, const float* cb, float* offc){
  __shared__ __align__(16) float wsh[4608];
  if (*flagp) conv_off_body((const float*)x, cw, cb, offc, wsh);
  else        conv_off_body((const bf16*)x, cw, cb, offc, wsh);
}

// ---------------------------------------------------------------------------
// K2: deformable conv, MFMA version. Block = (group g, 32 pixels).
// grid (512, 4), 256 thr. Gather: bilinear params in regs (clamped idx +
// zeroed weights), cols -> LDS bf16 [32 pos][584 ck] (pad 584 -> 2-way read
// conflicts = free). Einsum: M=64 co x N=32 p x K=576 via mfma 16x16x32 bf16:
// 4 waves, wave w = m-tile w, 2 n-tiles, 18 k-steps.
// ---------------------------------------------------------------------------
#define CROW 584

template<typename T>
__device__ __forceinline__ void deform_body(const T* __restrict__ x,
    const float* __restrict__ offc, const bf16* __restrict__ wdefb,
    float* __restrict__ xdir, unsigned short* cols){
  const int g = blockIdx.y;
  const int q0 = blockIdx.x * 32;
  const int b = q0 >> 12, p0 = q0 & 4095;
  const int t = threadIdx.x;

  // ---- gather phase ----
  {
    const int pos = t & 31, cb8 = t >> 5;         // cb8 in 0..7
    const int p = p0 + pos;
    const int y = p >> 6, xx = p & 63;
    const float* ob = offc + b * 18 * 4096 + p;
    const T* xg = x + ((b * 4 + g) * 64) * 4096;  // group channel base
    #pragma unroll
    for (int k = 0; k < 9; k++){
      float dy = ob[(2 * k) * 4096];
      float dx = ob[(2 * k + 1) * 4096];
      float py = (float)(y + k / 3 - 1) + dy;
      float px = (float)(xx + k % 3 - 1) + dx;
      float y0f = floorf(py), x0f = floorf(px);
      int y0 = (int)y0f, x0 = (int)x0f;
      float wy1 = py - y0f, wx1 = px - x0f;
      float wy0 = 1.f - wy1, wx0 = 1.f - wx1;
      bool vy0 = (unsigned)y0 < 64u, vy1 = (unsigned)(y0 + 1) < 64u;
      bool vx0 = (unsigned)x0 < 64u, vx1 = (unsigned)(x0 + 1) < 64u;
      float w00 = (vy0 && vx0) ? wy0 * wx0 : 0.f;
      float w01 = (vy0 && vx1) ? wy0 * wx1 : 0.f;
      float w10 = (vy1 && vx0) ? wy1 * wx0 : 0.f;
      float w11 = (vy1 && vx1) ? wy1 * wx1 : 0.f;
      int yc0 = min(max(y0, 0), 63), yc1 = min(max(y0 + 1, 0), 63);
      int xc0 = min(max(x0, 0), 63), xc1 = min(max(x0 + 1, 0), 63);
      int i00 = yc0 * 64 + xc0, i01 = yc0 * 64 + xc1;
      int i10 = yc1 * 64 + xc0, i11 = yc1 * 64 + xc1;
      #pragma unroll
      for (int u = 0; u < 8; u++){
        int cl = cb8 * 8 + u;
        const T* xc = xg + cl * 4096;
        float val = w00 * ldv(xc, i00) + w01 * ldv(xc, i01)
                  + w10 * ldv(xc, i10) + w11 * ldv(xc, i11);
        bf16 hv = __float2bfloat16(val);
        cols[pos * CROW + cl * 9 + k] = *(unsigned short*)&hv;
      }
    }
  }
  __syncthreads();

  // ---- MFMA phase ----
  {
    const int w = t >> 6;          // wave id = m-tile
    const int l = t & 63;
    const int lrow = l & 15;
    const int lhi = l >> 4;        // 0..3
    f32x4 acc0 = {0.f, 0.f, 0.f, 0.f};
    f32x4 acc1 = {0.f, 0.f, 0.f, 0.f};
    const bf16* wr = wdefb + (g * 64 + w * 16 + lrow) * 576;
    const unsigned short* b0p = cols + lrow * CROW;
    const unsigned short* b1p = cols + (16 + lrow) * CROW;
    #pragma unroll 2
    for (int kk = 0; kk < 576; kk += 32){
      int ko = kk + lhi * 8;
      short8 a  = *(const short8*)(wr + ko);
      short8 b0 = *(const short8*)(b0p + ko);
      short8 b1 = *(const short8*)(b1p + ko);
      acc0 = __builtin_amdgcn_mfma_f32_16x16x32_bf16(a, b0, acc0, 0, 0, 0);
      acc1 = __builtin_amdgcn_mfma_f32_16x16x32_bf16(a, b1, acc1, 0, 0, 0);
    }
    // C/D layout: col = lane&15 (pixel), row = (lane>>4)*4 + reg (co)
    const int co_base = g * 64 + w * 16 + lhi * 4;
    #pragma unroll
    for (int r = 0; r < 4; r++){
      float* xo = xdir + (b * 256 + co_base + r) * 4096 + p0 + lrow;
      xo[0]  = acc0[r];
      xo[16] = acc1[r];
    }
  }
}

__global__ __launch_bounds__(256) void k_deform(const void* x, const int* flagp,
    const float* offc, const bf16* wdefb, float* xdir){
  __shared__ __align__(16) unsigned short cols[32 * CROW];
  if (*flagp) deform_body((const float*)x, offc, wdefb, xdir, cols);
  else        deform_body((const bf16*)x, offc, wdefb, xdir, cols);
}

// ---------------------------------------------------------------------------
// K3: 1x1 conv over concat([x_dir, x_prev]) with w_cross (256x512), no bias.
// Block: 64 pixels x 64 co; thread: 4x4 microtile. grid (256, 4), 256 thr.
// ---------------------------------------------------------------------------
template<typename T>
__device__ __forceinline__ void cross_body(const float* __restrict__ xdir,
    const T* __restrict__ xprev, const float* __restrict__ wc,
    float* __restrict__ xdense, float* xs){
  const int q0 = blockIdx.x * 64;
  const int b = q0 >> 12, p0 = q0 & 4095;
  const int cg = blockIdx.y;
  const int t = threadIdx.x;
  const int pg = t & 15, cog = t >> 4;
  const int co_b = cg * 64 + cog * 4;
  float acc[16];
  #pragma unroll
  for (int i = 0; i < 16; i++) acc[i] = 0.f;
  for (int cc = 0; cc < 512; cc += 32){
    __syncthreads();
    for (int i = t; i < 2048; i += 256){
      int cl = i >> 6, pp = i & 63;
      int ci = cc + cl;
      xs[i] = (ci < 256) ? xdir[(b * 256 + ci) * 4096 + p0 + pp]
                         : ldv(xprev, (b * 256 + ci - 256) * 4096 + p0 + pp);
    }
    __syncthreads();
    for (int cl = 0; cl < 32; cl++){
      float4 xv = *(const float4*)(xs + cl * 64 + pg * 4);
      int ci = cc + cl;
      float w0 = wc[(co_b + 0) * 512 + ci];
      float w1 = wc[(co_b + 1) * 512 + ci];
      float w2 = wc[(co_b + 2) * 512 + ci];
      float w3 = wc[(co_b + 3) * 512 + ci];
      acc[ 0] += w0*xv.x; acc[ 1] += w0*xv.y; acc[ 2] += w0*xv.z; acc[ 3] += w0*xv.w;
      acc[ 4] += w1*xv.x; acc[ 5] += w1*xv.y; acc[ 6] += w1*xv.z; acc[ 7] += w1*xv.w;
      acc[ 8] += w2*xv.x; acc[ 9] += w2*xv.y; acc[10] += w2*xv.z; acc[11] += w2*xv.w;
      acc[12] += w3*xv.x; acc[13] += w3*xv.y; acc[14] += w3*xv.z; acc[15] += w3*xv.w;
    }
  }
  #pragma unroll
  for (int j = 0; j < 4; j++){
    float4 v; v.x = acc[j*4+0]; v.y = acc[j*4+1]; v.z = acc[j*4+2]; v.w = acc[j*4+3];
    *(float4*)(xdense + (b * 256 + co_b + j) * 4096 + p0 + pg * 4) = v;
  }
}

__global__ __launch_bounds__(256) void k_cross(const float* xdir, const void* xprev,
    const int* flagp, const float* wc, float* xdense){
  __shared__ __align__(16) float xs[2048];
  if (*flagp) cross_body(xdir, (const float*)xprev, wc, xdense, xs);
  else        cross_body(xdir, (const bf16*)xprev, wc, xdense, xs);
}

// ---------------------------------------------------------------------------
// K4: 3x3 conv 256->64 + bias + BN + SiLU. 4 co per block, weights in LDS.
// grid (16 ptiles, 16 cogroups, 4 b), 256 thr.
// ---------------------------------------------------------------------------
__global__ __launch_bounds__(256) void k_g1(
    const float* __restrict__ xdense, const float* __restrict__ cw,
    const float* __restrict__ cb,
    const float* __restrict__ gam, const float* __restrict__ bet,
    const float* __restrict__ mea, const float* __restrict__ var,
    float* __restrict__ abuf){
  const int b = blockIdx.z, cog = blockIdx.y, pt = blockIdx.x;
  const int co0 = cog * 4;
  __shared__ __align__(16) float wsh[2304 * 4];
  for (int i = threadIdx.x; i < 9216; i += 256){
    int ct = i >> 2, j = i & 3;
    wsh[i] = cw[(co0 + j) * 2304 + ct];
  }
  __syncthreads();
  const int p = pt * 256 + threadIdx.x;
  const int y = p >> 6, xx = p & 63;
  float acc[4] = {0,0,0,0};
  const float* xb = xdense + b * 256 * 4096;
  for (int ci = 0; ci < 256; ci++){
    const float* xc = xb + ci * 4096;
    #pragma unroll
    for (int t = 0; t < 9; t++){
      int yy = y + t / 3 - 1, xp = xx + t % 3 - 1;
      float xv = ((unsigned)yy < 64u && (unsigned)xp < 64u) ? xc[yy * 64 + xp] : 0.f;
      float4 wv = *(const float4*)(wsh + (ci * 9 + t) * 4);
      acc[0] += xv * wv.x; acc[1] += xv * wv.y; acc[2] += xv * wv.z; acc[3] += xv * wv.w;
    }
  }
  #pragma unroll
  for (int j = 0; j < 4; j++){
    int co = co0 + j;
    float v = acc[j] + cb[co];
    float inv = gam[co] * rsqrtf(var[co] + 1e-5f);
    v = v * inv + (bet[co] - mea[co] * inv);
    abuf[(b * 64 + co) * 4096 + p] = v * sigf(v);
  }
}

// ---------------------------------------------------------------------------
// K5: 1x1 conv 64->256 + bias + sigmoid, then xa = xdense * attn (fused).
// grid (64 ptiles, 64 cogroups of 4), 256 thr.
// ---------------------------------------------------------------------------
__global__ __launch_bounds__(256) void k_attn(
    const float* __restrict__ abuf, const float* __restrict__ cw,
    const float* __restrict__ cb, const float* __restrict__ xdense,
    float* __restrict__ xa){
  const int q0 = blockIdx.x * 256;
  const int b = q0 >> 12, p0 = q0 & 4095;
  const int co0 = blockIdx.y * 4;
  const int p = p0 + threadIdx.x;
  float acc[4] = {0,0,0,0};
  const float* ab = abuf + b * 64 * 4096;
  for (int c = 0; c < 64; c++){
    float av = ab[c * 4096 + p];
    acc[0] += cw[(co0 + 0) * 64 + c] * av;
    acc[1] += cw[(co0 + 1) * 64 + c] * av;
    acc[2] += cw[(co0 + 2) * 64 + c] * av;
    acc[3] += cw[(co0 + 3) * 64 + c] * av;
  }
  #pragma unroll
  for (int j = 0; j < 4; j++){
    int co = co0 + j;
    float attn = sigf(acc[j] + cb[co]);
    int idx = (b * 256 + co) * 4096 + p;
    xa[idx] = xdense[idx] * attn;
  }
}

// ---------------------------------------------------------------------------
// K6: 1x1 conv 256->256 + bias + BN + SiLU + residual, dual-mode store.
// grid (256, 4), 256 thr.
// ---------------------------------------------------------------------------
template<typename T>
__device__ __forceinline__ void out_body(const float* __restrict__ xa,
    const float* __restrict__ wo, const float* __restrict__ cb,
    const float* __restrict__ gam, const float* __restrict__ bet,
    const float* __restrict__ mea, const float* __restrict__ var,
    const T* __restrict__ xres, T* __restrict__ out, float* xs){
  const int q0 = blockIdx.x * 64;
  const int b = q0 >> 12, p0 = q0 & 4095;
  const int cg = blockIdx.y;
  const int t = threadIdx.x;
  const int pg = t & 15, cog = t >> 4;
  const int co_b = cg * 64 + cog * 4;
  float acc[16];
  #pragma unroll
  for (int i = 0; i < 16; i++) acc[i] = 0.f;
  for (int cc = 0; cc < 256; cc += 32){
    __syncthreads();
    for (int i = t; i < 2048; i += 256){
      int cl = i >> 6, pp = i & 63;
      xs[i] = xa[(b * 256 + cc + cl) * 4096 + p0 + pp];
    }
    __syncthreads();
    for (int cl = 0; cl < 32; cl++){
      float4 xv = *(const float4*)(xs + cl * 64 + pg * 4);
      int ci = cc + cl;
      float w0 = wo[(co_b + 0) * 256 + ci];
      float w1 = wo[(co_b + 1) * 256 + ci];
      float w2 = wo[(co_b + 2) * 256 + ci];
      float w3 = wo[(co_b + 3) * 256 + ci];
      acc[ 0] += w0*xv.x; acc[ 1] += w0*xv.y; acc[ 2] += w0*xv.z; acc[ 3] += w0*xv.w;
      acc[ 4] += w1*xv.x; acc[ 5] += w1*xv.y; acc[ 6] += w1*xv.z; acc[ 7] += w1*xv.w;
      acc[ 8] += w2*xv.x; acc[ 9] += w2*xv.y; acc[10] += w2*xv.z; acc[11] += w2*xv.w;
      acc[12] += w3*xv.x; acc[13] += w3*xv.y; acc[14] += w3*xv.z; acc[15] += w3*xv.w;
    }
  }
  #pragma unroll
  for (int j = 0; j < 4; j++){
    int co = co_b + j;
    float inv = gam[co] * rsqrtf(var[co] + 1e-5f);
    float sh  = bet[co] - mea[co] * inv;
    float bs  = cb[co];
    #pragma unroll
    for (int i = 0; i < 4; i++){
      float v = acc[j * 4 + i] + bs;
      v = v * inv + sh;
      v = v * sigf(v);
      int p = p0 + pg * 4 + i;
      int idx = (b * 256 + co) * 4096 + p;
      stv(out, idx, v + ldv(xres, idx));
    }
  }
}

__global__ __launch_bounds__(256) void k_out(const float* xa, const float* wo,
    const float* cb, const float* gam, const float* bet, const float* mea,
    const float* var, const void* xres, void* out, const int* flagp){
  __shared__ __align__(16) float xs[2048];
  if (*flagp) out_body(xa, wo, cb, gam, bet, mea, var, (const float*)xres, (float*)out, xs);
  else        out_body(xa, wo, cb, gam, bet, mea, var, (const bf16*)xres, (bf16*)out, xs);
}

// ---------------------------------------------------------------------------
extern "C" void kernel_launch(void* const* d_in, const int* in_sizes, int n_in,
                              void* d_out, int out_size, void* d_ws, size_t ws_size,
                              hipStream_t stream) {
  const void* x      = d_in[0];
  const void* x_prev = d_in[1];

  float* ws   = (float*)d_ws;
  int*   flag = (int*)ws;                 // ws[0..15] reserved
  float* cpar = ws + 16;                  // canonical fp32 params (551264 f)
  float* cw_off   = cpar + 0;
  float* cb_off   = cpar + 41472;
  float* cw_cross = cpar + 188960;
  float* cw_g1    = cpar + 320032;
  float* cb_g1    = cpar + 467488;
  float* cg1_gam  = cpar + 467552;
  float* cg1_bet  = cpar + 467616;
  float* cg1_mea  = cpar + 467680;
  float* cg1_var  = cpar + 467744;
  float* cw_g2    = cpar + 467808;
  float* cb_g2    = cpar + 484192;
  float* cw_out   = cpar + 484448;
  float* cb_out   = cpar + 549984;
  float* co_gam   = cpar + 550240;
  float* co_bet   = cpar + 550496;
  float* co_mea   = cpar + 550752;
  float* co_var   = cpar + 551008;

  bf16*  wdefb  = (bf16*)(ws + 16 + 551264);   // 147456 bf16 = 73728 floats
  float* base   = ws + 16 + 551264 + 73728;
  float* offc   = base;                   // 4*18*4096  = 294912 f
  float* xdir   = offc + 294912;          // 4*256*4096 = 4194304 f
  float* xdense = xdir + 4194304;         // 4194304 f
  float* abuf   = xdense + 4194304;       // 1048576 f
  float* xa     = xdir;                   // reuse (xdir dead after K3)

  ParamSrc ps;
  for (int i = 0; i < 18; i++) ps.p[i] = d_in[2 + i];

  k_detect<<<dim3(1), 256, 0, stream>>>((const unsigned short*)x, flag);
  k_convert<<<dim3(96, 19), 256, 0, stream>>>(ps, flag, cpar, wdefb);
  k_conv_off<<<dim3(16, 9, 4), 256, 0, stream>>>(x, flag, cw_off, cb_off, offc);
  k_deform<<<dim3(512, 4), 256, 0, stream>>>(x, flag, offc, wdefb, xdir);
  k_cross<<<dim3(256, 4), 256, 0, stream>>>(xdir, x_prev, flag, cw_cross, xdense);
  k_g1<<<dim3(16, 16, 4), 256, 0, stream>>>(xdense, cw_g1, cb_g1, cg1_gam, cg1_bet,
                                            cg1_mea, cg1_var, abuf);
  k_attn<<<dim3(64, 64), 256, 0, stream>>>(abuf, cw_g2, cb_g2, xdense, xa);
  k_out<<<dim3(256, 4), 256, 0, stream>>>(xa, cw_out, cb_out, co_gam, co_bet,
                                          co_mea, co_var, x, d_out, flag);
}

// Round 4
// 528.820 us; speedup vs baseline: 1.5149x; 1.2532x over previous
//
#include <hip/hip_runtime.h>
#include <hip/hip_bf16.h>

using bf16 = __hip_bfloat16;
typedef __attribute__((ext_vector_type(8))) short short8;
typedef __attribute__((ext_vector_type(4))) float f32x4;

__device__ __forceinline__ float b2f(bf16 v){ return __bfloat162float(v); }
__device__ __forceinline__ float sigf(float v){ return 1.f/(1.f + __expf(-v)); }
__device__ __forceinline__ float ldv(const float* p, int i){ return p[i]; }
__device__ __forceinline__ float ldv(const bf16* p, int i){ return b2f(p[i]); }
__device__ __forceinline__ void stv(float* p, int i, float v){ p[i] = v; }
__device__ __forceinline__ void stv(bf16* p, int i, float v){ p[i] = __float2bfloat16(v); }

// ---------------------------------------------------------------------------
// K0: dtype detect. flag=1 => inputs are f32.
// ---------------------------------------------------------------------------
__global__ __launch_bounds__(256) void k_detect(const unsigned short* xs, int* flag){
  __shared__ int cnt;
  if (threadIdx.x == 0) cnt = 0;
  __syncthreads();
  int local = 0;
  for (int i = threadIdx.x; i < 16384; i += 256){
    if (((xs[i] >> 7) & 0xFF) == 0xFF) local++;
  }
  if (local) atomicAdd(&cnt, local);
  __syncthreads();
  if (threadIdx.x == 0) *flag = (cnt > 0) ? 1 : 0;
}

// ---------------------------------------------------------------------------
// K0b: canonicalize params. slots 0-17: fp32 in cpar; 18: w_def->bf16;
// 19: w_off->bf16 padded 18->32 rows; 20: w_g1->bf16. grid (96, 21).
// ---------------------------------------------------------------------------
struct ParamSrc { const void* p[18]; };

__global__ __launch_bounds__(256) void k_convert(ParamSrc ps, const int* flagp,
    float* cpar, bf16* wdefb, bf16* woffb, bf16* wg1b){
  static constexpr int n[21]   = {41472,18,147456,131072,147456,64,64,64,64,64,
                                  16384,256,65536,256,256,256,256,256,
                                  147456,73728,147456};
  static constexpr int off[18] = {0,41472,41504,188960,320032,467488,467552,467616,
                                  467680,467744,467808,484192,484448,549984,550240,
                                  550496,550752,551008};
  const int s = blockIdx.y;
  const bool f32 = (*flagp != 0);
  if (s >= 18){
    const int src_slot = (s == 18) ? 2 : ((s == 19) ? 0 : 4);
    bf16* dst = (s == 18) ? wdefb : ((s == 19) ? woffb : wg1b);
    const int nsrc = (s == 19) ? 41472 : n[s];
    if (f32){
      const float* src = (const float*)ps.p[src_slot];
      for (int i = blockIdx.x * 256 + threadIdx.x; i < n[s]; i += gridDim.x * 256)
        dst[i] = (i < nsrc) ? __float2bfloat16(src[i]) : __float2bfloat16(0.f);
    } else {
      const bf16* src = (const bf16*)ps.p[src_slot];
      for (int i = blockIdx.x * 256 + threadIdx.x; i < n[s]; i += gridDim.x * 256)
        dst[i] = (i < nsrc) ? src[i] : __float2bfloat16(0.f);
    }
    return;
  }
  float* dst = cpar + off[s];
  if (f32){
    const float* src = (const float*)ps.p[s];
    for (int i = blockIdx.x * 256 + threadIdx.x; i < n[s]; i += gridDim.x * 256)
      dst[i] = src[i];
  } else {
    const bf16* src = (const bf16*)ps.p[s];
    for (int i = blockIdx.x * 256 + threadIdx.x; i < n[s]; i += gridDim.x * 256)
      dst[i] = b2f(src[i]);
  }
}

// ---------------------------------------------------------------------------
// Generic 3x3 pad=1 conv via im2col + MFMA. Block = one image row (64 px),
// 256 thr, grid 256 (b*64+y). K=2304 in 8 chunks of 288 (32 ch x 9 taps).
// LDS cols layout [k][pos] (pad 68): pixel-pair-packed b32 writes are
// conflict-free; B-frag u16 reads are 2-way (free). A-frags: bf16 weights
// from global (L2-resident). COT = #16-co m-tiles. EPI: BN+SiLU epilogue.
// ---------------------------------------------------------------------------
template<typename T, int COT, bool EPI>
__device__ __forceinline__ void conv3_body(const T* __restrict__ xin,
    const bf16* __restrict__ wb, const float* __restrict__ cbv,
    const float* __restrict__ gam, const float* __restrict__ bet,
    const float* __restrict__ mea, const float* __restrict__ var,
    float* __restrict__ outp, int co_lim, unsigned short* cols){
  const int bx = blockIdx.x;
  const int b = bx >> 6, y = bx & 63;
  const int t = threadIdx.x;
  const int l = t & 63, w = t >> 6;
  const int lm = l & 15, lq = l >> 4;
  const int pos2 = t & 31, kq = t >> 5;
  unsigned int* cols32 = (unsigned int*)cols;
  f32x4 acc[COT];
  #pragma unroll
  for (int m = 0; m < COT; m++) acc[m] = (f32x4){0.f,0.f,0.f,0.f};

  for (int cc = 0; cc < 256; cc += 32){
    __syncthreads();
    // ---- gather: 4 channels (kq*4..+4) x 9 taps x pixel pair (2*pos2, +1)
    #pragma unroll
    for (int c8 = 0; c8 < 4; c8++){
      const int c_local = kq * 4 + c8;
      const T* xc = xin + (b * 256 + cc + c_local) * 4096;
      #pragma unroll
      for (int tap = 0; tap < 9; tap++){
        const int ti = tap / 3, tj = tap % 3;
        const int yy = y + ti - 1;
        const int px0 = 2 * pos2 + tj - 1;
        const bool vy = (unsigned)yy < 64u;
        float v0 = (vy && (unsigned)px0 < 64u) ? ldv(xc, yy * 64 + px0) : 0.f;
        float v1 = (vy && (unsigned)(px0 + 1) < 64u) ? ldv(xc, yy * 64 + px0 + 1) : 0.f;
        bf16 h0 = __float2bfloat16(v0), h1 = __float2bfloat16(v1);
        unsigned int packed = (unsigned int)*(unsigned short*)&h0
                            | ((unsigned int)*(unsigned short*)&h1 << 16);
        cols32[(c_local * 9 + tap) * 34 + pos2] = packed;
      }
    }
    __syncthreads();
    // ---- MFMA: 9 ksteps of 32 over this chunk
    #pragma unroll
    for (int kk = 0; kk < 288; kk += 32){
      short8 bfr;
      #pragma unroll
      for (int j = 0; j < 8; j++)
        bfr[j] = (short)cols[(kk + lq * 8 + j) * 68 + w * 16 + lm];
      #pragma unroll
      for (int m = 0; m < COT; m++){
        const bf16* ap = wb + (m * 16 + lm) * 2304 + cc * 9 + kk + lq * 8;
        short8 afr = *(const short8*)ap;
        acc[m] = __builtin_amdgcn_mfma_f32_16x16x32_bf16(afr, bfr, acc[m], 0, 0, 0);
      }
    }
  }
  // ---- epilogue: D col=lane&15 (pixel), row=(lane>>4)*4+reg (co)
  const int p = y * 64 + w * 16 + lm;
  #pragma unroll
  for (int m = 0; m < COT; m++){
    #pragma unroll
    for (int r = 0; r < 4; r++){
      const int co = m * 16 + lq * 4 + r;
      if (co >= co_lim) continue;
      float v = acc[m][r] + cbv[co];
      if constexpr (EPI){
        float inv = gam[co] * rsqrtf(var[co] + 1e-5f);
        v = v * inv + (bet[co] - mea[co] * inv);
        v = v * sigf(v);
      }
      outp[(b * co_lim + co) * 4096 + p] = v;
    }
  }
}

__global__ __launch_bounds__(256) void k_coff_m(const void* x, const int* flagp,
    const bf16* woffb, const float* cb, float* offc){
  __shared__ __align__(16) unsigned short cols[288 * 68];
  if (*flagp) conv3_body<float, 2, false>((const float*)x, woffb, cb,
                  nullptr, nullptr, nullptr, nullptr, offc, 18, cols);
  else        conv3_body<bf16, 2, false>((const bf16*)x, woffb, cb,
                  nullptr, nullptr, nullptr, nullptr, offc, 18, cols);
}

__global__ __launch_bounds__(256) void k_g1_m(const float* xdense,
    const bf16* wg1b, const float* cb, const float* gam, const float* bet,
    const float* mea, const float* var, float* abuf){
  __shared__ __align__(16) unsigned short cols[288 * 68];
  conv3_body<float, 4, true>(xdense, wg1b, cb, gam, bet, mea, var, abuf, 64, cols);
}

// ---------------------------------------------------------------------------
// K2: deformable conv, MFMA (unchanged from R3 — passed).
// ---------------------------------------------------------------------------
#define CROW 584

template<typename T>
__device__ __forceinline__ void deform_body(const T* __restrict__ x,
    const float* __restrict__ offc, const bf16* __restrict__ wdefb,
    float* __restrict__ xdir, unsigned short* cols){
  const int g = blockIdx.y;
  const int q0 = blockIdx.x * 32;
  const int b = q0 >> 12, p0 = q0 & 4095;
  const int t = threadIdx.x;
  {
    const int pos = t & 31, cb8 = t >> 5;
    const int p = p0 + pos;
    const int y = p >> 6, xx = p & 63;
    const float* ob = offc + b * 18 * 4096 + p;
    const T* xg = x + ((b * 4 + g) * 64) * 4096;
    #pragma unroll
    for (int k = 0; k < 9; k++){
      float dy = ob[(2 * k) * 4096];
      float dx = ob[(2 * k + 1) * 4096];
      float py = (float)(y + k / 3 - 1) + dy;
      float px = (float)(xx + k % 3 - 1) + dx;
      float y0f = floorf(py), x0f = floorf(px);
      int y0 = (int)y0f, x0 = (int)x0f;
      float wy1 = py - y0f, wx1 = px - x0f;
      float wy0 = 1.f - wy1, wx0 = 1.f - wx1;
      bool vy0 = (unsigned)y0 < 64u, vy1 = (unsigned)(y0 + 1) < 64u;
      bool vx0 = (unsigned)x0 < 64u, vx1 = (unsigned)(x0 + 1) < 64u;
      float w00 = (vy0 && vx0) ? wy0 * wx0 : 0.f;
      float w01 = (vy0 && vx1) ? wy0 * wx1 : 0.f;
      float w10 = (vy1 && vx0) ? wy1 * wx0 : 0.f;
      float w11 = (vy1 && vx1) ? wy1 * wx1 : 0.f;
      int yc0 = min(max(y0, 0), 63), yc1 = min(max(y0 + 1, 0), 63);
      int xc0 = min(max(x0, 0), 63), xc1 = min(max(x0 + 1, 0), 63);
      int i00 = yc0 * 64 + xc0, i01 = yc0 * 64 + xc1;
      int i10 = yc1 * 64 + xc0, i11 = yc1 * 64 + xc1;
      #pragma unroll
      for (int u = 0; u < 8; u++){
        int cl = cb8 * 8 + u;
        const T* xc = xg + cl * 4096;
        float val = w00 * ldv(xc, i00) + w01 * ldv(xc, i01)
                  + w10 * ldv(xc, i10) + w11 * ldv(xc, i11);
        bf16 hv = __float2bfloat16(val);
        cols[pos * CROW + cl * 9 + k] = *(unsigned short*)&hv;
      }
    }
  }
  __syncthreads();
  {
    const int w = t >> 6;
    const int l = t & 63;
    const int lrow = l & 15;
    const int lhi = l >> 4;
    f32x4 acc0 = {0.f, 0.f, 0.f, 0.f};
    f32x4 acc1 = {0.f, 0.f, 0.f, 0.f};
    const bf16* wr = wdefb + (g * 64 + w * 16 + lrow) * 576;
    const unsigned short* b0p = cols + lrow * CROW;
    const unsigned short* b1p = cols + (16 + lrow) * CROW;
    #pragma unroll 2
    for (int kk = 0; kk < 576; kk += 32){
      int ko = kk + lhi * 8;
      short8 a  = *(const short8*)(wr + ko);
      short8 b0 = *(const short8*)(b0p + ko);
      short8 b1 = *(const short8*)(b1p + ko);
      acc0 = __builtin_amdgcn_mfma_f32_16x16x32_bf16(a, b0, acc0, 0, 0, 0);
      acc1 = __builtin_amdgcn_mfma_f32_16x16x32_bf16(a, b1, acc1, 0, 0, 0);
    }
    const int co_base = g * 64 + w * 16 + lhi * 4;
    #pragma unroll
    for (int r = 0; r < 4; r++){
      float* xo = xdir + (b * 256 + co_base + r) * 4096 + p0 + lrow;
      xo[0]  = acc0[r];
      xo[16] = acc1[r];
    }
  }
}

__global__ __launch_bounds__(256) void k_deform(const void* x, const int* flagp,
    const float* offc, const bf16* wdefb, float* xdir){
  __shared__ __align__(16) unsigned short cols[32 * CROW];
  if (*flagp) deform_body((const float*)x, offc, wdefb, xdir, cols);
  else        deform_body((const bf16*)x, offc, wdefb, xdir, cols);
}

// ---------------------------------------------------------------------------
// K3: 1x1 conv concat([x_dir, x_prev]) * w_cross (256x512). grid (256,4).
// ---------------------------------------------------------------------------
template<typename T>
__device__ __forceinline__ void cross_body(const float* __restrict__ xdir,
    const T* __restrict__ xprev, const float* __restrict__ wc,
    float* __restrict__ xdense, float* xs){
  const int q0 = blockIdx.x * 64;
  const int b = q0 >> 12, p0 = q0 & 4095;
  const int cg = blockIdx.y;
  const int t = threadIdx.x;
  const int pg = t & 15, cog = t >> 4;
  const int co_b = cg * 64 + cog * 4;
  float acc[16];
  #pragma unroll
  for (int i = 0; i < 16; i++) acc[i] = 0.f;
  for (int cc = 0; cc < 512; cc += 32){
    __syncthreads();
    for (int i = t; i < 2048; i += 256){
      int cl = i >> 6, pp = i & 63;
      int ci = cc + cl;
      xs[i] = (ci < 256) ? xdir[(b * 256 + ci) * 4096 + p0 + pp]
                         : ldv(xprev, (b * 256 + ci - 256) * 4096 + p0 + pp);
    }
    __syncthreads();
    for (int cl = 0; cl < 32; cl++){
      float4 xv = *(const float4*)(xs + cl * 64 + pg * 4);
      int ci = cc + cl;
      float w0 = wc[(co_b + 0) * 512 + ci];
      float w1 = wc[(co_b + 1) * 512 + ci];
      float w2 = wc[(co_b + 2) * 512 + ci];
      float w3 = wc[(co_b + 3) * 512 + ci];
      acc[ 0] += w0*xv.x; acc[ 1] += w0*xv.y; acc[ 2] += w0*xv.z; acc[ 3] += w0*xv.w;
      acc[ 4] += w1*xv.x; acc[ 5] += w1*xv.y; acc[ 6] += w1*xv.z; acc[ 7] += w1*xv.w;
      acc[ 8] += w2*xv.x; acc[ 9] += w2*xv.y; acc[10] += w2*xv.z; acc[11] += w2*xv.w;
      acc[12] += w3*xv.x; acc[13] += w3*xv.y; acc[14] += w3*xv.z; acc[15] += w3*xv.w;
    }
  }
  #pragma unroll
  for (int j = 0; j < 4; j++){
    float4 v; v.x = acc[j*4+0]; v.y = acc[j*4+1]; v.z = acc[j*4+2]; v.w = acc[j*4+3];
    *(float4*)(xdense + (b * 256 + co_b + j) * 4096 + p0 + pg * 4) = v;
  }
}

__global__ __launch_bounds__(256) void k_cross(const float* xdir, const void* xprev,
    const int* flagp, const float* wc, float* xdense){
  __shared__ __align__(16) float xs[2048];
  if (*flagp) cross_body(xdir, (const float*)xprev, wc, xdense, xs);
  else        cross_body(xdir, (const bf16*)xprev, wc, xdense, xs);
}

// ---------------------------------------------------------------------------
// K5: 1x1 conv 64->256 + bias + sigmoid, xa = xdense * attn. grid (64,64).
// ---------------------------------------------------------------------------
__global__ __launch_bounds__(256) void k_attn(
    const float* __restrict__ abuf, const float* __restrict__ cw,
    const float* __restrict__ cb, const float* __restrict__ xdense,
    float* __restrict__ xa){
  const int q0 = blockIdx.x * 256;
  const int b = q0 >> 12, p0 = q0 & 4095;
  const int co0 = blockIdx.y * 4;
  const int p = p0 + threadIdx.x;
  float acc[4] = {0,0,0,0};
  const float* ab = abuf + b * 64 * 4096;
  for (int c = 0; c < 64; c++){
    float av = ab[c * 4096 + p];
    acc[0] += cw[(co0 + 0) * 64 + c] * av;
    acc[1] += cw[(co0 + 1) * 64 + c] * av;
    acc[2] += cw[(co0 + 2) * 64 + c] * av;
    acc[3] += cw[(co0 + 3) * 64 + c] * av;
  }
  #pragma unroll
  for (int j = 0; j < 4; j++){
    int co = co0 + j;
    float attn = sigf(acc[j] + cb[co]);
    int idx = (b * 256 + co) * 4096 + p;
    xa[idx] = xdense[idx] * attn;
  }
}

// ---------------------------------------------------------------------------
// K6: 1x1 conv 256->256 + bias + BN + SiLU + residual. grid (256,4).
// ---------------------------------------------------------------------------
template<typename T>
__device__ __forceinline__ void out_body(const float* __restrict__ xa,
    const float* __restrict__ wo, const float* __restrict__ cb,
    const float* __restrict__ gam, const float* __restrict__ bet,
    const float* __restrict__ mea, const float* __restrict__ var,
    const T* __restrict__ xres, T* __restrict__ out, float* xs){
  const int q0 = blockIdx.x * 64;
  const int b = q0 >> 12, p0 = q0 & 4095;
  const int cg = blockIdx.y;
  const int t = threadIdx.x;
  const int pg = t & 15, cog = t >> 4;
  const int co_b = cg * 64 + cog * 4;
  float acc[16];
  #pragma unroll
  for (int i = 0; i < 16; i++) acc[i] = 0.f;
  for (int cc = 0; cc < 256; cc += 32){
    __syncthreads();
    for (int i = t; i < 2048; i += 256){
      int cl = i >> 6, pp = i & 63;
      xs[i] = xa[(b * 256 + cc + cl) * 4096 + p0 + pp];
    }
    __syncthreads();
    for (int cl = 0; cl < 32; cl++){
      float4 xv = *(const float4*)(xs + cl * 64 + pg * 4);
      int ci = cc + cl;
      float w0 = wo[(co_b + 0) * 256 + ci];
      float w1 = wo[(co_b + 1) * 256 + ci];
      float w2 = wo[(co_b + 2) * 256 + ci];
      float w3 = wo[(co_b + 3) * 256 + ci];
      acc[ 0] += w0*xv.x; acc[ 1] += w0*xv.y; acc[ 2] += w0*xv.z; acc[ 3] += w0*xv.w;
      acc[ 4] += w1*xv.x; acc[ 5] += w1*xv.y; acc[ 6] += w1*xv.z; acc[ 7] += w1*xv.w;
      acc[ 8] += w2*xv.x; acc[ 9] += w2*xv.y; acc[10] += w2*xv.z; acc[11] += w2*xv.w;
      acc[12] += w3*xv.x; acc[13] += w3*xv.y; acc[14] += w3*xv.z; acc[15] += w3*xv.w;
    }
  }
  #pragma unroll
  for (int j = 0; j < 4; j++){
    int co = co_b + j;
    float inv = gam[co] * rsqrtf(var[co] + 1e-5f);
    float sh  = bet[co] - mea[co] * inv;
    float bs  = cb[co];
    #pragma unroll
    for (int i = 0; i < 4; i++){
      float v = acc[j * 4 + i] + bs;
      v = v * inv + sh;
      v = v * sigf(v);
      int p = p0 + pg * 4 + i;
      int idx = (b * 256 + co) * 4096 + p;
      stv(out, idx, v + ldv(xres, idx));
    }
  }
}

__global__ __launch_bounds__(256) void k_out(const float* xa, const float* wo,
    const float* cb, const float* gam, const float* bet, const float* mea,
    const float* var, const void* xres, void* out, const int* flagp){
  __shared__ __align__(16) float xs[2048];
  if (*flagp) out_body(xa, wo, cb, gam, bet, mea, var, (const float*)xres, (float*)out, xs);
  else        out_body(xa, wo, cb, gam, bet, mea, var, (const bf16*)xres, (bf16*)out, xs);
}

// ---------------------------------------------------------------------------
extern "C" void kernel_launch(void* const* d_in, const int* in_sizes, int n_in,
                              void* d_out, int out_size, void* d_ws, size_t ws_size,
                              hipStream_t stream) {
  const void* x      = d_in[0];
  const void* x_prev = d_in[1];

  float* ws   = (float*)d_ws;
  int*   flag = (int*)ws;                 // ws[0..15] reserved
  float* cpar = ws + 16;                  // canonical fp32 params (551264 f)
  float* cb_off   = cpar + 41472;
  float* cw_cross = cpar + 188960;
  float* cb_g1    = cpar + 467488;
  float* cg1_gam  = cpar + 467552;
  float* cg1_bet  = cpar + 467616;
  float* cg1_mea  = cpar + 467680;
  float* cg1_var  = cpar + 467744;
  float* cw_g2    = cpar + 467808;
  float* cb_g2    = cpar + 484192;
  float* cw_out   = cpar + 484448;
  float* cb_out   = cpar + 549984;
  float* co_gam   = cpar + 550240;
  float* co_bet   = cpar + 550496;
  float* co_mea   = cpar + 550752;
  float* co_var   = cpar + 551008;

  bf16*  wdefb  = (bf16*)(ws + 16 + 551264);            // 147456 hw = 73728 f
  bf16*  woffb  = (bf16*)(ws + 16 + 551264 + 73728);    // 73728 hw  = 36864 f
  bf16*  wg1b   = (bf16*)(ws + 16 + 551264 + 73728 + 36864); // 147456 hw = 73728 f
  float* base   = ws + 16 + 551264 + 73728 + 36864 + 73728;
  float* offc   = base;                   // 4*18*4096  = 294912 f
  float* xdir   = offc + 294912;          // 4*256*4096 = 4194304 f
  float* xdense = xdir + 4194304;         // 4194304 f
  float* abuf   = xdense + 4194304;       // 1048576 f
  float* xa     = xdir;                   // reuse (xdir dead after K3)

  ParamSrc ps;
  for (int i = 0; i < 18; i++) ps.p[i] = d_in[2 + i];

  k_detect<<<dim3(1), 256, 0, stream>>>((const unsigned short*)x, flag);
  k_convert<<<dim3(96, 21), 256, 0, stream>>>(ps, flag, cpar, wdefb, woffb, wg1b);
  k_coff_m<<<dim3(256), 256, 0, stream>>>(x, flag, woffb, cb_off, offc);
  k_deform<<<dim3(512, 4), 256, 0, stream>>>(x, flag, offc, wdefb, xdir);
  k_cross<<<dim3(256, 4), 256, 0, stream>>>(xdir, x_prev, flag, cw_cross, xdense);
  k_g1_m<<<dim3(256), 256, 0, stream>>>(xdense, wg1b, cb_g1, cg1_gam, cg1_bet,
                                        cg1_mea, cg1_var, abuf);
  k_attn<<<dim3(64, 64), 256, 0, stream>>>(abuf, cw_g2, cb_g2, xdense, xa);
  k_out<<<dim3(256, 4), 256, 0, stream>>>(xa, cw_out, cb_out, co_gam, co_bet,
                                          co_mea, co_var, x, d_out, flag);
}